// Round 8
// baseline (2146.320 us; speedup 1.0000x reference)
//
#include <hip/hip_runtime.h>
#include <hip/hip_fp16.h>
#include <cstdint>
#include <cstddef>

typedef _Float16 f16;
typedef _Float16 f16x2 __attribute__((ext_vector_type(2)));
typedef _Float16 f16x4 __attribute__((ext_vector_type(4)));
typedef _Float16 f16x8 __attribute__((ext_vector_type(8)));
typedef int i32x4 __attribute__((ext_vector_type(4)));

#define S_LEN 2048
#define BATCH 64
#define I_DIM 128
#define H_DIM 512
#define O_DIM 64

// v_dot2_f32_f16 (fp32 accumulate — used in the small GEMMs only).
__device__ __forceinline__ float fdot2f(f16x2 a, f16x2 b, float c) {
#if __has_builtin(__builtin_amdgcn_fdot2)
    return __builtin_amdgcn_fdot2(a, b, c, false);
#else
    return c + (float)a.x * (float)b.x + (float)a.y * (float)b.y;
#endif
}

// v_dot4_i32_i8: 4-way i8 MAC, i32 accumulate.
__device__ __forceinline__ int sdot4(int a, int b, int c) {
#if __has_builtin(__builtin_amdgcn_sdot4)
    return __builtin_amdgcn_sdot4(a, b, c, false);
#else
    int r = c;
#pragma unroll
    for (int i = 0; i < 4; ++i) {
        int av = (a << (24 - 8 * i)) >> 24;
        int bv = (b << (24 - 8 * i)) >> 24;
        r += av * bv;
    }
    return r;
#endif
}

// DPP quad_perm cross-lane (xor1: 0xB1, xor2: 0x4E) — VALU, no LDS.
template <int CTRL>
__device__ __forceinline__ int dpp_qi(int v) {
    return __builtin_amdgcn_update_dpp(0, v, CTRL, 0xF, 0xF, true);
}

// ---------------------------------------------------------------------------
// Phase 1: u[row][c] = sum_k x[row][k] * Wih[k][c], rows = B*S, K=128, N=512.
// (unchanged)
// ---------------------------------------------------------------------------
__global__ __launch_bounds__(256)
void u_gemm_kernel(const float* __restrict__ x, const float* __restrict__ Wih,
                   f16* __restrict__ u) {
    const int tid = threadIdx.x;
    const int r0 = blockIdx.x * 32;
    const int c0 = blockIdx.y * 128;

    __shared__ __align__(16) f16x2 wih_s[I_DIM / 2][128];
    __shared__ __align__(16) f16x2 x_s[32][I_DIM / 2];

#pragma unroll
    for (int i = 0; i < 32; ++i) {
        int idx = i * 256 + tid;
        int kp = idx >> 7;
        int cl = idx & 127;
        float w0 = Wih[(size_t)(2 * kp + 0) * H_DIM + c0 + cl];
        float w1 = Wih[(size_t)(2 * kp + 1) * H_DIM + c0 + cl];
        f16x2 w; w.x = (f16)w0; w.y = (f16)w1;
        wih_s[kp][cl] = w;
    }
    const float4* xs = (const float4*)(x + (size_t)r0 * I_DIM);
    f16x4* xd = (f16x4*)x_s;
#pragma unroll
    for (int i = 0; i < 4; ++i) {
        int idx = i * 256 + tid;
        float4 v = xs[idx];
        f16x4 h; h.x = (f16)v.x; h.y = (f16)v.y; h.z = (f16)v.z; h.w = (f16)v.w;
        xd[idx] = h;
    }
    __syncthreads();

    const int cl = tid & 127;
    const int rh = tid >> 7;
    float acc[16];
#pragma unroll
    for (int r = 0; r < 16; ++r) acc[r] = 0.f;

#pragma unroll
    for (int kc = 0; kc < 2; ++kc) {
        f16x2 wv[32];
#pragma unroll
        for (int i = 0; i < 32; ++i) wv[i] = wih_s[kc * 32 + i][cl];
#pragma unroll
        for (int r = 0; r < 16; ++r) {
            const int row = rh * 16 + r;
#pragma unroll
            for (int m = 0; m < 8; ++m) {
                f16x8 h8v = *(const f16x8*)(&x_s[row][kc * 32 + 4 * m]);
                const f16x2* hp = (const f16x2*)&h8v;
                acc[r] = fdot2f(wv[4 * m + 0], hp[0], acc[r]);
                acc[r] = fdot2f(wv[4 * m + 1], hp[1], acc[r]);
                acc[r] = fdot2f(wv[4 * m + 2], hp[2], acc[r]);
                acc[r] = fdot2f(wv[4 * m + 3], hp[3], acc[r]);
            }
        }
    }
#pragma unroll
    for (int r = 0; r < 16; ++r) {
        int row = r0 + rh * 16 + r;
        u[(size_t)row * H_DIM + c0 + cl] = (f16)acc[r];
    }
}

// ---------------------------------------------------------------------------
// Phase 2: scan via v_dot4_i32_i8, 1024 threads, W live-set < 128 VGPRs.
//
// R5-R7 post-mortem: VGPR_Count pinned at 128 regardless of launch-bounds /
// waves_per_eu attributes, dur flat at 1750us with VALU-busy ~2x the source
// instruction count. Whether the excess is AGPR-parking (accvgpr_read per
// wq use) or sub-rate sdot4, the robust move is to FIT in 128 arch regs by
// construction and double wave parallelism:
//
// 1024 threads = 16 waves (4/SIMD at <=128 regs, pool 512). Thread
// (kg=tid&3, cq=tid>>2 in [0,256)): K-slice [kg*128, kg*128+128) of TWO
// columns {cq, cq+256} -> wq[32][2] = 64 W-regs (half of R5-R7). av read in
// 2 chunks of 4 (peak ~20 regs). Total live ~110 < 128: nothing parked.
// Per-CU sdot4 issue is invariant (1024 wave-insts/step = 512cy floor).
//
// Quad butterfly (DPP xor1+xor2) completes both column sums in all 4 quad
// lanes; owners kg<2 keep column c_own = cq + 256*kg (covers all 512 cols
// exactly once), do tanh, write h8 byte + coalesced hs store. Quantization
// identical to R5 (passed, absmax 0.0078).
// ---------------------------------------------------------------------------
#define SLICE_STRIDE 144   // 128 B data + 16 B pad per K-slice

__global__ __launch_bounds__(1024, 4)
void rnn_scan_kernel(const float* __restrict__ Wrec, f16* __restrict__ uhs) {
    const int tid = threadIdx.x;          // 0..1023
    const int b = blockIdx.x;
    const int kg = tid & 3;               // K-slice
    const int cq = tid >> 2;              // 0..255 column base

    __shared__ __align__(16) signed char h8[2][4 * SLICE_STRIDE];
    __shared__ float colmax[512];

    // ---- pass 1: per-column max, coalesced (threads 0..511) ----
    if (tid < 512) {
        const float* wp = Wrec + tid;
        float m0 = 0.f, m1 = 0.f, m2 = 0.f, m3 = 0.f;
        for (int k = 0; k < 512; k += 4) {
            m0 = fmaxf(m0, __builtin_fabsf(wp[(size_t)(k + 0) * H_DIM]));
            m1 = fmaxf(m1, __builtin_fabsf(wp[(size_t)(k + 1) * H_DIM]));
            m2 = fmaxf(m2, __builtin_fabsf(wp[(size_t)(k + 2) * H_DIM]));
            m3 = fmaxf(m3, __builtin_fabsf(wp[(size_t)(k + 3) * H_DIM]));
        }
        float m = fmaxf(fmaxf(m0, m1), fmaxf(m2, m3));
        colmax[tid] = fmaxf(m, 1e-20f);
    }
    // zero h buffer 0 — ALL 576 bytes (R4 lesson: cover the padded tail).
    if (tid < 4 * SLICE_STRIDE) h8[0][tid] = 0;
    __syncthreads();

    // ---- pass 2: quantize + pack W ----
    // wq[q][i]: dword q packs k = kg*128 + 4q .. +3 (byte e -> k+e) for
    // column c_i = cq + 256*i.
    int wq[32][2];   // 64 VGPRs
#pragma unroll
    for (int i = 0; i < 2; ++i) {
        const int col = cq + 256 * i;
        const float* wp = Wrec + col;
        const float sc = 127.f / colmax[col];
#pragma unroll
        for (int q = 0; q < 32; ++q) {
            int wd = 0;
#pragma unroll
            for (int e = 0; e < 4; ++e) {
                float v = wp[(size_t)(kg * 128 + 4 * q + e) * H_DIM] * sc;
                v = fminf(fmaxf(v, -127.f), 127.f);
                wd |= (((int)rintf(v)) & 255) << (8 * e);
            }
            wq[q][i] = wd;
        }
    }

    // owners: kg<2 own column c_own = cq + 256*kg (all 512 cols, once each)
    const bool own = (kg < 2);
    const int c_own = cq + 256 * kg;
    const int c_safe = own ? c_own : cq;
    f16* io = uhs + (size_t)b * S_LEN * H_DIM + c_safe;
    const float inv = colmax[c_safe] * (1.f / 16129.f);   // colmax/127^2

    float hp = 0.f;
    float uc = 0.f;
    f16 ua = (f16)0.f;
    if (own) {
        uc = (float)io[0];
        if (S_LEN > 1) ua = io[H_DIM];
    }

    __syncthreads();

#define DOT8(AV, QB)                                                          \
    ac0 = sdot4(AV[0], wq[(QB) + 0][0], ac0);                                 \
    ac1 = sdot4(AV[0], wq[(QB) + 0][1], ac1);                                 \
    ac0 = sdot4(AV[1], wq[(QB) + 1][0], ac0);                                 \
    ac1 = sdot4(AV[1], wq[(QB) + 1][1], ac1);                                 \
    ac0 = sdot4(AV[2], wq[(QB) + 2][0], ac0);                                 \
    ac1 = sdot4(AV[2], wq[(QB) + 2][1], ac1);                                 \
    ac0 = sdot4(AV[3], wq[(QB) + 3][0], ac0);                                 \
    ac1 = sdot4(AV[3], wq[(QB) + 3][1], ac1);

    for (int t = 0; t < S_LEN; ++t) {
        // prefetch u(t+2)
        f16 ub = (f16)0.f;
        if (own && t + 2 < S_LEN) ub = io[(size_t)(t + 2) * H_DIM];

        const signed char* hb = h8[t & 1] + kg * SLICE_STRIDE;
        int ac0 = 0, ac1 = 0;

        // chunk A: k-bytes 0..63 of this slice (broadcast b128 reads)
        {
            i32x4 a0 = *(const i32x4*)(hb + 0);
            i32x4 a1 = *(const i32x4*)(hb + 16);
            i32x4 a2 = *(const i32x4*)(hb + 32);
            i32x4 a3 = *(const i32x4*)(hb + 48);
            DOT8(a0, 0)
            DOT8(a1, 4)
            DOT8(a2, 8)
            DOT8(a3, 12)
        }
        // chunk B: k-bytes 64..127
        {
            i32x4 a4 = *(const i32x4*)(hb + 64);
            i32x4 a5 = *(const i32x4*)(hb + 80);
            i32x4 a6 = *(const i32x4*)(hb + 96);
            i32x4 a7 = *(const i32x4*)(hb + 112);
            DOT8(a4, 16)
            DOT8(a5, 20)
            DOT8(a6, 24)
            DOT8(a7, 28)
        }

        // quad butterfly: sum the 4 kg partials (all quad lanes get both sums)
        ac0 += dpp_qi<0xB1>(ac0);  ac1 += dpp_qi<0xB1>(ac1);
        ac0 += dpp_qi<0x4E>(ac0);  ac1 += dpp_qi<0x4E>(ac1);

        if (own) {
            int zi = (kg == 0) ? ac0 : ac1;
            float z = (float)zi * inv + uc;

            // tanh(z) = 1 - 2/(exp(2z)+1)
            float e2 = __expf(2.f * z);
            float r = 1.f - 2.f * __builtin_amdgcn_rcpf(e2 + 1.f);
            hp = 0.8f * hp + 0.2f * r;

            // next h: slice c>>7, offset c&127
            h8[(t + 1) & 1][(c_own >> 7) * SLICE_STRIDE + (c_own & 127)] =
                (signed char)(int)rintf(hp * 127.f);
            io[(size_t)t * H_DIM] = (f16)hp;  // hs (f16, phase-3 input)

            uc = (float)ua;
            ua = ub;
        }
        __syncthreads();
    }
#undef DOT8
}

// ---------------------------------------------------------------------------
// Phase 3: out[row][o] = sum_k hs[row][k] * Who[k][o], K=512, O=64, fp32 out.
// (unchanged)
// ---------------------------------------------------------------------------
__global__ __launch_bounds__(256)
void out_gemm_kernel(const f16* __restrict__ hs, const float* __restrict__ Who,
                     float* __restrict__ out) {
    const int tid = threadIdx.x;
    const int r0 = blockIdx.x * 32;

    __shared__ __align__(16) f16x2 who_s[128][O_DIM];
    __shared__ __align__(16) f16x2 hs_s[32][128];

    const int o = tid & 63;
    const int rg = tid >> 6;

    float acc[8];
#pragma unroll
    for (int r = 0; r < 8; ++r) acc[r] = 0.f;

    for (int kc = 0; kc < 2; ++kc) {
        if (kc) __syncthreads();
#pragma unroll
        for (int i = 0; i < 32; ++i) {
            int idx = i * 256 + tid;
            int kp = idx >> 6;
            int oc = idx & 63;
            float w0 = Who[(size_t)(kc * 256 + 2 * kp + 0) * O_DIM + oc];
            float w1 = Who[(size_t)(kc * 256 + 2 * kp + 1) * O_DIM + oc];
            f16x2 wv2; wv2.x = (f16)w0; wv2.y = (f16)w1;
            who_s[kp][oc] = wv2;
        }
        f16x8* hd = (f16x8*)hs_s;
#pragma unroll
        for (int i = 0; i < 4; ++i) {
            int idx = i * 256 + tid;
            int r = idx >> 5;
            int m = idx & 31;
            f16x8 v = *(const f16x8*)(hs + (size_t)(r0 + r) * H_DIM + kc * 256 + m * 8);
            hd[idx] = v;
        }
        __syncthreads();

#pragma unroll
        for (int sc = 0; sc < 4; ++sc) {
            f16x2 wv[32];
#pragma unroll
            for (int i = 0; i < 32; ++i) wv[i] = who_s[sc * 32 + i][o];
#pragma unroll
            for (int r = 0; r < 8; ++r) {
                const int row = rg * 8 + r;
#pragma unroll
                for (int m = 0; m < 8; ++m) {
                    f16x8 h8v = *(const f16x8*)(&hs_s[row][sc * 32 + 4 * m]);
                    const f16x2* hp = (const f16x2*)&h8v;
                    acc[r] = fdot2f(wv[4 * m + 0], hp[0], acc[r]);
                    acc[r] = fdot2f(wv[4 * m + 1], hp[1], acc[r]);
                    acc[r] = fdot2f(wv[4 * m + 2], hp[2], acc[r]);
                    acc[r] = fdot2f(wv[4 * m + 3], hp[3], acc[r]);
                }
            }
        }
    }
#pragma unroll
    for (int r = 0; r < 8; ++r) {
        int row = r0 + rg * 8 + r;
        out[(size_t)row * O_DIM + o] = acc[r];
    }
}

extern "C" void kernel_launch(void* const* d_in, const int* in_sizes, int n_in,
                              void* d_out, int out_size, void* d_ws, size_t ws_size,
                              hipStream_t stream) {
    const float* x    = (const float*)d_in[0];   // [64][2048][128]
    const float* Wih  = (const float*)d_in[1];   // [128][512]
    const float* Wrec = (const float*)d_in[2];   // [512][512]
    const float* Who  = (const float*)d_in[3];   // [512][64]
    float* out = (float*)d_out;                  // [64][2048][64]
    f16* uhs = (f16*)d_ws;                       // 128 MB: u, then hs in-place

    const int R = BATCH * S_LEN;

    u_gemm_kernel<<<dim3(R / 32, H_DIM / 128), 256, 0, stream>>>(x, Wih, uhs);
    rnn_scan_kernel<<<dim3(BATCH), 1024, 0, stream>>>(Wrec, uhs);
    out_gemm_kernel<<<dim3(R / 32), 256, 0, stream>>>(uhs, Who, out);
}

// Round 10
// 1760.606 us; speedup vs baseline: 1.2191x; 1.2191x over previous
//
#include <hip/hip_runtime.h>
#include <hip/hip_fp16.h>
#include <cstdint>
#include <cstddef>

typedef _Float16 f16;
typedef _Float16 f16x2 __attribute__((ext_vector_type(2)));
typedef _Float16 f16x4 __attribute__((ext_vector_type(4)));
typedef _Float16 f16x8 __attribute__((ext_vector_type(8)));
typedef int i32x4 __attribute__((ext_vector_type(4)));
typedef float f32x4 __attribute__((ext_vector_type(4)));

#define S_LEN 2048
#define BATCH 64
#define I_DIM 128
#define H_DIM 512
#define O_DIM 64

// v_dot2_f32_f16 (fp32 accumulate — used in phase 3 only).
__device__ __forceinline__ float fdot2f(f16x2 a, f16x2 b, float c) {
#if __has_builtin(__builtin_amdgcn_fdot2)
    return __builtin_amdgcn_fdot2(a, b, c, false);
#else
    return c + (float)a.x * (float)b.x + (float)a.y * (float)b.y;
#endif
}

// ---------------------------------------------------------------------------
// Phase 1: u = x @ Wih via mfma_f32_16x16x32_f16.
// rows = B*S = 131072, K = 128, N = 512.
//
// WG 256 thr = 4 waves; tile 64 rows x 128 cols, full K (no K staging loop).
// A-frags (x rows) loaded reg-direct from global (f32->f16 convert): lane
// holds x[r0 + w*16 + (l&15)][kt*32 + (l>>4)*8 .. +7]. B-frags from a
// per-WG LDS-transposed Wih tile bT[c][k] with XOR slot swizzle
// (k ^ ((c&7)<<3), 16B-slot granular) to break the bank aliasing of the
// 256B row stride (without swizzle all 16 li-lanes hit one bank).
// Both operands use the SAME nominal lane->k map, so any internal HW k
// permutation cancels (proven on this HW by R1/R3 passing). D layout
// (verified m89): col = lane&15, row = (lane>>4)*4 + reg.
// ---------------------------------------------------------------------------
__global__ __launch_bounds__(256)
void u_gemm_kernel(const float* __restrict__ x, const float* __restrict__ Wih,
                   f16* __restrict__ u) {
    const int tid = threadIdx.x;
    const int lane = tid & 63;
    const int w = tid >> 6;               // wave 0..3
    const int li = lane & 15;
    const int g = lane >> 4;              // 0..3
    const size_t r0 = (size_t)blockIdx.x * 64;
    const int c0 = blockIdx.y * 128;

    // bT[c][k]: transposed Wih tile, 128x128 f16, XOR-swizzled k slots.
    __shared__ __align__(16) f16 bT[128 * 128];

    // stage: idx = i*256+tid -> k = idx>>7, c = idx&127 (coalesced global read)
#pragma unroll
    for (int i = 0; i < 64; ++i) {
        int idx = i * 256 + tid;
        int k = idx >> 7;
        int c = idx & 127;
        float v = Wih[(size_t)k * H_DIM + c0 + c];
        bT[c * 128 + (k ^ ((c & 7) << 3))] = (f16)v;
    }

    // A-frags: this lane's x row, 4 kt slots of 8 f16
    const int tr = (int)r0 + w * 16 + li;
    f16x8 a[4];
#pragma unroll
    for (int kt = 0; kt < 4; ++kt) {
        const float* xp = x + (size_t)tr * I_DIM + kt * 32 + g * 8;
        f32x4 v0 = *(const f32x4*)(xp);
        f32x4 v1 = *(const f32x4*)(xp + 4);
        f16x8 h;
        h[0] = (f16)v0[0]; h[1] = (f16)v0[1]; h[2] = (f16)v0[2]; h[3] = (f16)v0[3];
        h[4] = (f16)v1[0]; h[5] = (f16)v1[1]; h[6] = (f16)v1[2]; h[7] = (f16)v1[3];
        a[kt] = h;
    }
    __syncthreads();

    f32x4 acc[8];
#pragma unroll
    for (int n = 0; n < 8; ++n) acc[n] = (f32x4){0.f, 0.f, 0.f, 0.f};

#pragma unroll
    for (int kt = 0; kt < 4; ++kt) {
#pragma unroll
        for (int n = 0; n < 8; ++n) {
            const int c = n * 16 + li;
            const int koff = (kt * 32 + g * 8) ^ ((c & 7) << 3);
            f16x8 b = *(const f16x8*)(&bT[c * 128 + koff]);
            acc[n] = __builtin_amdgcn_mfma_f32_16x16x32_f16(a[kt], b, acc[n], 0, 0, 0);
        }
    }

    // store: D row = (l>>4)*4 + reg, col = li
#pragma unroll
    for (int n = 0; n < 8; ++n) {
#pragma unroll
        for (int r = 0; r < 4; ++r) {
            size_t row = r0 + w * 16 + g * 4 + r;
            u[row * H_DIM + c0 + n * 16 + li] = (f16)acc[n][r];
        }
    }
}

// ---------------------------------------------------------------------------
// Phase 2: scan via int8 MFMA, W register/AGPR-resident, 8 waves (2/SIMD).
// VERBATIM the R3 kernel (measured 1571us scan, passed, absmax 0.0078).
// Why this beats every VALU-sdot variant (R5-R8: 1750-1810us): the compiler
// caps arch VGPRs at 128 and parks wf[] in AGPRs; MFMA reads AGPR operands
// directly (free), v_dot4 cannot (accvgpr_read per use / scratch spills).
// ---------------------------------------------------------------------------
__global__ __launch_bounds__(512, 2)
void rnn_scan_kernel(const float* __restrict__ Wrec, f16* __restrict__ uhs) {
    const int tid = threadIdx.x;          // 0..511
    const int b = blockIdx.x;
    const int l = tid & 63;
    const int w = tid >> 6;               // wave 0..7
    const int grp = l >> 4;               // 0..3
    const int li = l & 15;

    __shared__ __align__(16) signed char h8[2][512];   // double-buffered h (i8)
    __shared__ float colmax[512];

    // ---- pass 1: per-column max, coalesced (thread tid scans column tid) ----
    {
        const float* wp = Wrec + tid;
        float m0 = 0.f, m1 = 0.f, m2 = 0.f, m3 = 0.f;
        for (int k = 0; k < 512; k += 4) {
            m0 = fmaxf(m0, __builtin_fabsf(wp[(size_t)(k + 0) * H_DIM]));
            m1 = fmaxf(m1, __builtin_fabsf(wp[(size_t)(k + 1) * H_DIM]));
            m2 = fmaxf(m2, __builtin_fabsf(wp[(size_t)(k + 2) * H_DIM]));
            m3 = fmaxf(m3, __builtin_fabsf(wp[(size_t)(k + 3) * H_DIM]));
        }
        float m = fmaxf(fmaxf(m0, m1), fmaxf(m2, m3));
        colmax[tid] = fmaxf(m, 1e-20f);
    }
    h8[0][tid] = 0;                       // zero h buffer 0 (512 threads cover)
    __syncthreads();

    // ---- pass 2: quantize + pack W into register B-fragments ----
    // frag (kt, j): lane holds W[kt*32 + grp*8 + jj][w*64 + j*16 + li],
    // jj=0..7 packed little-endian (byte jj -> dword jj>>2).
    i32x4 wf[8][4];   // 128 regs (AGPR-parked by the compiler; fine for MFMA)
#pragma unroll
    for (int j = 0; j < 4; ++j) {
        const int col = w * 64 + j * 16 + li;
        const float* wp = Wrec + col;
        const float sc = 127.f / colmax[col];
#pragma unroll
        for (int kt = 0; kt < 8; ++kt) {
            int wd0 = 0, wd1 = 0, wd2 = 0, wd3 = 0;
#pragma unroll
            for (int jj = 0; jj < 16; ++jj) {
                float v = wp[(size_t)(kt * 64 + grp * 16 + jj) * H_DIM] * sc;
                v = fminf(fmaxf(v, -127.f), 127.f);
                int q = ((int)rintf(v)) & 255;
                int sh = 8 * (jj & 3);
                if (jj < 4)       wd0 |= q << sh;
                else if (jj < 8)  wd1 |= q << sh;
                else if (jj < 12) wd2 |= q << sh;
                else              wd3 |= q << sh;
            }
            i32x4 f; f.x = wd0; f.y = wd1; f.z = wd2; f.w = wd3;
            wf[kt][j] = f;
        }
    }

    // this thread's output column: c = w*64 + grp*16 + li == tid (j = grp)
    f16* io = uhs + (size_t)b * S_LEN * H_DIM + tid;
    const float inv = colmax[tid] * (1.f / 16129.f);   // colmax[c]/127^2

    float hp = 0.f;
    float uc = (float)io[0];
    f16 ua = (f16)0.f;
    if (S_LEN > 1) ua = io[H_DIM];

    __syncthreads();

    for (int t = 0; t < S_LEN; ++t) {
        // prefetch u(t+2)
        f16 ub = (f16)0.f;
        if (t + 2 < S_LEN) ub = io[(size_t)(t + 2) * H_DIM];

        const signed char* hb = h8[t & 1];
        // A-frags: h8[kt*64 + grp*16 .. +15], broadcast within 16-lane group.
        i32x4 av[8];
#pragma unroll
        for (int kt = 0; kt < 8; ++kt)
            av[kt] = *(const i32x4*)(hb + kt * 64 + grp * 16);

        i32x4 a0 = {0,0,0,0}, a1 = {0,0,0,0}, a2 = {0,0,0,0}, a3 = {0,0,0,0};
#pragma unroll
        for (int kt = 0; kt < 8; ++kt) {
            a0 = __builtin_amdgcn_mfma_i32_16x16x64_i8(av[kt], wf[kt][0], a0, 0, 0, 0);
            a1 = __builtin_amdgcn_mfma_i32_16x16x64_i8(av[kt], wf[kt][1], a1, 0, 0, 0);
            a2 = __builtin_amdgcn_mfma_i32_16x16x64_i8(av[kt], wf[kt][2], a2, 0, 0, 0);
            a3 = __builtin_amdgcn_mfma_i32_16x16x64_i8(av[kt], wf[kt][3], a3, 0, 0, 0);
        }

        // replicated-A: all D rows equal -> reg 0 of tile j=grp is lane's z
        int zi = grp == 0 ? a0[0] : grp == 1 ? a1[0] : grp == 2 ? a2[0] : a3[0];
        float z = (float)zi * inv + uc;

        // tanh(z) = 1 - 2/(exp(2z)+1)
        float e2 = __expf(2.f * z);
        float r = 1.f - 2.f * __builtin_amdgcn_rcpf(e2 + 1.f);
        hp = 0.8f * hp + 0.2f * r;

        h8[(t + 1) & 1][tid] = (signed char)(int)rintf(hp * 127.f);
        io[(size_t)t * H_DIM] = (f16)hp;      // hs (f16, phase-3 input)

        uc = (float)ua;
        ua = ub;
        __syncthreads();
    }
}

// ---------------------------------------------------------------------------
// Phase 3: out[row][o] = sum_k hs[row][k] * Who[k][o], K=512, O=64, fp32 out.
// (unchanged)
// ---------------------------------------------------------------------------
__global__ __launch_bounds__(256)
void out_gemm_kernel(const f16* __restrict__ hs, const float* __restrict__ Who,
                     float* __restrict__ out) {
    const int tid = threadIdx.x;
    const int r0 = blockIdx.x * 32;

    __shared__ __align__(16) f16x2 who_s[128][O_DIM];
    __shared__ __align__(16) f16x2 hs_s[32][128];

    const int o = tid & 63;
    const int rg = tid >> 6;

    float acc[8];
#pragma unroll
    for (int r = 0; r < 8; ++r) acc[r] = 0.f;

    for (int kc = 0; kc < 2; ++kc) {
        if (kc) __syncthreads();
#pragma unroll
        for (int i = 0; i < 32; ++i) {
            int idx = i * 256 + tid;
            int kp = idx >> 6;
            int oc = idx & 63;
            float w0 = Who[(size_t)(kc * 256 + 2 * kp + 0) * O_DIM + oc];
            float w1 = Who[(size_t)(kc * 256 + 2 * kp + 1) * O_DIM + oc];
            f16x2 wv2; wv2.x = (f16)w0; wv2.y = (f16)w1;
            who_s[kp][oc] = wv2;
        }
        f16x8* hd = (f16x8*)hs_s;
#pragma unroll
        for (int i = 0; i < 4; ++i) {
            int idx = i * 256 + tid;
            int r = idx >> 5;
            int m = idx & 31;
            f16x8 v = *(const f16x8*)(hs + (size_t)(r0 + r) * H_DIM + kc * 256 + m * 8);
            hd[idx] = v;
        }
        __syncthreads();

#pragma unroll
        for (int sc = 0; sc < 4; ++sc) {
            f16x2 wv[32];
#pragma unroll
            for (int i = 0; i < 32; ++i) wv[i] = who_s[sc * 32 + i][o];
#pragma unroll
            for (int r = 0; r < 8; ++r) {
                const int row = rg * 8 + r;
#pragma unroll
                for (int m = 0; m < 8; ++m) {
                    f16x8 h8v = *(const f16x8*)(&hs_s[row][sc * 32 + 4 * m]);
                    const f16x2* hp = (const f16x2*)&h8v;
                    acc[r] = fdot2f(wv[4 * m + 0], hp[0], acc[r]);
                    acc[r] = fdot2f(wv[4 * m + 1], hp[1], acc[r]);
                    acc[r] = fdot2f(wv[4 * m + 2], hp[2], acc[r]);
                    acc[r] = fdot2f(wv[4 * m + 3], hp[3], acc[r]);
                }
            }
        }
    }
#pragma unroll
    for (int r = 0; r < 8; ++r) {
        int row = r0 + rg * 8 + r;
        out[(size_t)row * O_DIM + o] = acc[r];
    }
}

extern "C" void kernel_launch(void* const* d_in, const int* in_sizes, int n_in,
                              void* d_out, int out_size, void* d_ws, size_t ws_size,
                              hipStream_t stream) {
    const float* x    = (const float*)d_in[0];   // [64][2048][128]
    const float* Wih  = (const float*)d_in[1];   // [128][512]
    const float* Wrec = (const float*)d_in[2];   // [512][512]
    const float* Who  = (const float*)d_in[3];   // [512][64]
    float* out = (float*)d_out;                  // [64][2048][64]
    f16* uhs = (f16*)d_ws;                       // 128 MB: u, then hs in-place

    const int R = BATCH * S_LEN;

    u_gemm_kernel<<<dim3(R / 64, H_DIM / 128), 256, 0, stream>>>(x, Wih, uhs);
    rnn_scan_kernel<<<dim3(BATCH), 512, 0, stream>>>(Wrec, uhs);
    out_gemm_kernel<<<dim3(R / 32), 256, 0, stream>>>(uhs, Who, out);
}

// Round 11
// 1670.326 us; speedup vs baseline: 1.2850x; 1.0540x over previous
//
#include <hip/hip_runtime.h>
#include <hip/hip_fp16.h>
#include <cstdint>
#include <cstddef>

typedef _Float16 f16;
typedef _Float16 f16x2 __attribute__((ext_vector_type(2)));
typedef _Float16 f16x4 __attribute__((ext_vector_type(4)));
typedef _Float16 f16x8 __attribute__((ext_vector_type(8)));
typedef int i32x4 __attribute__((ext_vector_type(4)));
typedef float f32x4 __attribute__((ext_vector_type(4)));

#define S_LEN 2048
#define BATCH 64
#define I_DIM 128
#define H_DIM 512
#define O_DIM 64

// ---------------------------------------------------------------------------
// Phase 1: u = x @ Wih via mfma_f32_16x16x32_f16.  (unchanged from R10 —
// passed, absmax 0.0078; this A/B/D lane mapping is hardware-verified.)
// ---------------------------------------------------------------------------
__global__ __launch_bounds__(256)
void u_gemm_kernel(const float* __restrict__ x, const float* __restrict__ Wih,
                   f16* __restrict__ u) {
    const int tid = threadIdx.x;
    const int lane = tid & 63;
    const int w = tid >> 6;               // wave 0..3
    const int li = lane & 15;
    const int g = lane >> 4;              // 0..3
    const size_t r0 = (size_t)blockIdx.x * 64;
    const int c0 = blockIdx.y * 128;

    // bT[c][k]: transposed Wih tile, 128x128 f16, XOR-swizzled k slots.
    __shared__ __align__(16) f16 bT[128 * 128];

#pragma unroll
    for (int i = 0; i < 64; ++i) {
        int idx = i * 256 + tid;
        int k = idx >> 7;
        int c = idx & 127;
        float v = Wih[(size_t)k * H_DIM + c0 + c];
        bT[c * 128 + (k ^ ((c & 7) << 3))] = (f16)v;
    }

    const int tr = (int)r0 + w * 16 + li;
    f16x8 a[4];
#pragma unroll
    for (int kt = 0; kt < 4; ++kt) {
        const float* xp = x + (size_t)tr * I_DIM + kt * 32 + g * 8;
        f32x4 v0 = *(const f32x4*)(xp);
        f32x4 v1 = *(const f32x4*)(xp + 4);
        f16x8 h;
        h[0] = (f16)v0[0]; h[1] = (f16)v0[1]; h[2] = (f16)v0[2]; h[3] = (f16)v0[3];
        h[4] = (f16)v1[0]; h[5] = (f16)v1[1]; h[6] = (f16)v1[2]; h[7] = (f16)v1[3];
        a[kt] = h;
    }
    __syncthreads();

    f32x4 acc[8];
#pragma unroll
    for (int n = 0; n < 8; ++n) acc[n] = (f32x4){0.f, 0.f, 0.f, 0.f};

#pragma unroll
    for (int kt = 0; kt < 4; ++kt) {
#pragma unroll
        for (int n = 0; n < 8; ++n) {
            const int c = n * 16 + li;
            const int koff = (kt * 32 + g * 8) ^ ((c & 7) << 3);
            f16x8 b = *(const f16x8*)(&bT[c * 128 + koff]);
            acc[n] = __builtin_amdgcn_mfma_f32_16x16x32_f16(a[kt], b, acc[n], 0, 0, 0);
        }
    }

#pragma unroll
    for (int n = 0; n < 8; ++n) {
#pragma unroll
        for (int r = 0; r < 4; ++r) {
            size_t row = r0 + w * 16 + g * 4 + r;
            u[row * H_DIM + c0 + n * 16 + li] = (f16)acc[n][r];
        }
    }
}

// ---------------------------------------------------------------------------
// Phase 2: scan via int8 MFMA (R3/R10 body, measured 1533us) + ONE change:
// the per-step global h-store is DEFERRED to after the next barrier.
// __syncthreads() drains vmcnt(0); previously the 2B io store issued right
// before the barrier put its L2-commit latency on every step's critical
// path. Now hh is kept in a register and stored at the TOP of the next
// iteration — the store gets a full step (~1700cy) to retire. Each thread
// reads/writes only its own column of io, so the reorder is race-free.
// ---------------------------------------------------------------------------
__global__ __launch_bounds__(512, 2)
void rnn_scan_kernel(const float* __restrict__ Wrec, f16* __restrict__ uhs) {
    const int tid = threadIdx.x;          // 0..511
    const int b = blockIdx.x;
    const int l = tid & 63;
    const int w = tid >> 6;               // wave 0..7
    const int grp = l >> 4;               // 0..3
    const int li = l & 15;

    __shared__ __align__(16) signed char h8[2][512];   // double-buffered h (i8)
    __shared__ float colmax[512];

    // ---- pass 1: per-column max, coalesced (thread tid scans column tid) ----
    {
        const float* wp = Wrec + tid;
        float m0 = 0.f, m1 = 0.f, m2 = 0.f, m3 = 0.f;
        for (int k = 0; k < 512; k += 4) {
            m0 = fmaxf(m0, __builtin_fabsf(wp[(size_t)(k + 0) * H_DIM]));
            m1 = fmaxf(m1, __builtin_fabsf(wp[(size_t)(k + 1) * H_DIM]));
            m2 = fmaxf(m2, __builtin_fabsf(wp[(size_t)(k + 2) * H_DIM]));
            m3 = fmaxf(m3, __builtin_fabsf(wp[(size_t)(k + 3) * H_DIM]));
        }
        float m = fmaxf(fmaxf(m0, m1), fmaxf(m2, m3));
        colmax[tid] = fmaxf(m, 1e-20f);
    }
    h8[0][tid] = 0;                       // zero h buffer 0 (512 threads cover)
    __syncthreads();

    // ---- pass 2: quantize + pack W into register B-fragments ----
    i32x4 wf[8][4];   // 128 regs (AGPR-parked by the compiler; fine for MFMA)
#pragma unroll
    for (int j = 0; j < 4; ++j) {
        const int col = w * 64 + j * 16 + li;
        const float* wp = Wrec + col;
        const float sc = 127.f / colmax[col];
#pragma unroll
        for (int kt = 0; kt < 8; ++kt) {
            int wd0 = 0, wd1 = 0, wd2 = 0, wd3 = 0;
#pragma unroll
            for (int jj = 0; jj < 16; ++jj) {
                float v = wp[(size_t)(kt * 64 + grp * 16 + jj) * H_DIM] * sc;
                v = fminf(fmaxf(v, -127.f), 127.f);
                int q = ((int)rintf(v)) & 255;
                int sh = 8 * (jj & 3);
                if (jj < 4)       wd0 |= q << sh;
                else if (jj < 8)  wd1 |= q << sh;
                else if (jj < 12) wd2 |= q << sh;
                else              wd3 |= q << sh;
            }
            i32x4 f; f.x = wd0; f.y = wd1; f.z = wd2; f.w = wd3;
            wf[kt][j] = f;
        }
    }

    // this thread's output column: c = w*64 + grp*16 + li == tid (j = grp)
    f16* io = uhs + (size_t)b * S_LEN * H_DIM + tid;
    const float inv = colmax[tid] * (1.f / 16129.f);   // colmax[c]/127^2

    float hp = 0.f;
    f16 hh_prev = (f16)0.f;               // deferred-store buffer
    float uc = (float)io[0];
    f16 ua = (f16)0.f;
    if (S_LEN > 1) ua = io[H_DIM];

    __syncthreads();

    for (int t = 0; t < S_LEN; ++t) {
        // deferred store of h(t-1) — issued AFTER the barrier that ended
        // step t-1, so its vmcnt drain lands a full step later.
        if (t > 0) io[(size_t)(t - 1) * H_DIM] = hh_prev;

        // prefetch u(t+2)
        f16 ub = (f16)0.f;
        if (t + 2 < S_LEN) ub = io[(size_t)(t + 2) * H_DIM];

        const signed char* hb = h8[t & 1];
        // A-frags: h8[kt*64 + grp*16 .. +15], broadcast within 16-lane group.
        i32x4 av[8];
#pragma unroll
        for (int kt = 0; kt < 8; ++kt)
            av[kt] = *(const i32x4*)(hb + kt * 64 + grp * 16);

        i32x4 a0 = {0,0,0,0}, a1 = {0,0,0,0}, a2 = {0,0,0,0}, a3 = {0,0,0,0};
#pragma unroll
        for (int kt = 0; kt < 8; ++kt) {
            a0 = __builtin_amdgcn_mfma_i32_16x16x64_i8(av[kt], wf[kt][0], a0, 0, 0, 0);
            a1 = __builtin_amdgcn_mfma_i32_16x16x64_i8(av[kt], wf[kt][1], a1, 0, 0, 0);
            a2 = __builtin_amdgcn_mfma_i32_16x16x64_i8(av[kt], wf[kt][2], a2, 0, 0, 0);
            a3 = __builtin_amdgcn_mfma_i32_16x16x64_i8(av[kt], wf[kt][3], a3, 0, 0, 0);
        }

        // replicated-A: all D rows equal -> reg 0 of tile j=grp is lane's z
        int zi = grp == 0 ? a0[0] : grp == 1 ? a1[0] : grp == 2 ? a2[0] : a3[0];
        float z = (float)zi * inv + uc;

        // tanh(z) = 1 - 2/(exp(2z)+1)
        float e2 = __expf(2.f * z);
        float r = 1.f - 2.f * __builtin_amdgcn_rcpf(e2 + 1.f);
        hp = 0.8f * hp + 0.2f * r;
        f16 hh = (f16)hp;

        h8[(t + 1) & 1][tid] = (signed char)(int)rintf(hp * 127.f);
        hh_prev = hh;                     // global store happens next iteration

        uc = (float)ua;
        ua = ub;
        __syncthreads();
    }
    io[(size_t)(S_LEN - 1) * H_DIM] = hh_prev;   // epilogue: last h
}

// ---------------------------------------------------------------------------
// Phase 3: out = hs @ Who via mfma_f32_16x16x32_f16.
// rows = 131072, K = 512, N = 64.  Memory-bound: 128MB hs + 32MB out ~ 25us
// floor. Same hardware-verified lane mapping as phase 1:
//   A: lane holds hs[r0 + w*16 + (l&15)][kt*32 + (l>>4)*8 .. +7] (f16 direct)
//   B: LDS-transposed Who tile bT[c][k], XOR slot swizzle k^((c&7)<<3)
//      (row stride 1024B -> same-bank without swizzle; with it, 2-way = free)
//   D: row = (l>>4)*4 + reg, col = n*16 + (l&15); f32 stores.
// Who re-read per WG (128KB) is L2-resident (<< 4MB/XCD).
// ---------------------------------------------------------------------------
__global__ __launch_bounds__(256)
void out_gemm_kernel(const f16* __restrict__ hs, const float* __restrict__ Who,
                     float* __restrict__ out) {
    const int tid = threadIdx.x;
    const int lane = tid & 63;
    const int w = tid >> 6;               // wave 0..3
    const int li = lane & 15;
    const int g = lane >> 4;              // 0..3
    const size_t r0 = (size_t)blockIdx.x * 64;

    __shared__ __align__(16) f16 bT[64 * 512];   // 64 KB

    // stage WhoT: idx -> k = idx>>6, c = idx&63 (coalesced global read)
#pragma unroll 4
    for (int i = 0; i < 128; ++i) {
        int idx = i * 256 + tid;
        int k = idx >> 6;
        int c = idx & 63;
        float v = Who[(size_t)k * O_DIM + c];
        bT[c * 512 + (k ^ ((c & 7) << 3))] = (f16)v;
    }

    const size_t tr = r0 + w * 16 + li;
    const f16* ap = hs + tr * H_DIM + g * 8;

    __syncthreads();

    f32x4 acc[4];
#pragma unroll
    for (int n = 0; n < 4; ++n) acc[n] = (f32x4){0.f, 0.f, 0.f, 0.f};

#pragma unroll
    for (int kt = 0; kt < 16; ++kt) {
        f16x8 a = *(const f16x8*)(ap + kt * 32);
#pragma unroll
        for (int n = 0; n < 4; ++n) {
            const int c = n * 16 + li;
            const int koff = (kt * 32 + g * 8) ^ ((c & 7) << 3);
            f16x8 b = *(const f16x8*)(&bT[c * 512 + koff]);
            acc[n] = __builtin_amdgcn_mfma_f32_16x16x32_f16(a, b, acc[n], 0, 0, 0);
        }
    }

    // store: D row = (l>>4)*4 + reg, col = n*16 + li (f32)
#pragma unroll
    for (int n = 0; n < 4; ++n) {
#pragma unroll
        for (int r = 0; r < 4; ++r) {
            size_t row = r0 + w * 16 + g * 4 + r;
            out[row * O_DIM + n * 16 + li] = acc[n][r];
        }
    }
}

extern "C" void kernel_launch(void* const* d_in, const int* in_sizes, int n_in,
                              void* d_out, int out_size, void* d_ws, size_t ws_size,
                              hipStream_t stream) {
    const float* x    = (const float*)d_in[0];   // [64][2048][128]
    const float* Wih  = (const float*)d_in[1];   // [128][512]
    const float* Wrec = (const float*)d_in[2];   // [512][512]
    const float* Who  = (const float*)d_in[3];   // [512][64]
    float* out = (float*)d_out;                  // [64][2048][64]
    f16* uhs = (f16*)d_ws;                       // 128 MB: u, then hs in-place

    const int R = BATCH * S_LEN;

    u_gemm_kernel<<<dim3(R / 64, H_DIM / 128), 256, 0, stream>>>(x, Wih, uhs);
    rnn_scan_kernel<<<dim3(BATCH), 512, 0, stream>>>(Wrec, uhs);
    out_gemm_kernel<<<dim3(R / 64), 256, 0, stream>>>(uhs, Who, out);
}